// Round 1
// baseline (556.988 us; speedup 1.0000x reference)
//
#include <hip/hip_runtime.h>

// Problem constants (fixed shapes from setup_inputs)
constexpr int B  = 4;
constexpr int N  = 16384;   // dense points
constexpr int S  = 4096;    // sparse points
constexpr int CD = 128;     // dense feature channels
constexpr int CS = 256;     // sparse feature channels
constexpr int CO = 128;     // output channels
constexpr int CIN = CD + CS; // 384

// ---------------------------------------------------------------------------
// K1: KNN (top-3 smallest squared distances) + normalized inverse-distance
// weights. One thread per dense point; sparse xyz staged in LDS (64KB).
// ---------------------------------------------------------------------------
__global__ __launch_bounds__(256) void knn_kernel(
    const float* __restrict__ dxyz, const float* __restrict__ sxyz,
    float* __restrict__ wgt, int* __restrict__ idx) {
  __shared__ float4 sp[S];
  const int b = blockIdx.y;
  const int n = blockIdx.x * 256 + threadIdx.x;
  const float* sb = sxyz + b * 3 * S;
  for (int s = threadIdx.x; s < S; s += 256) {
    sp[s] = make_float4(sb[s], sb[S + s], sb[2 * S + s], 0.f);
  }
  __syncthreads();

  const float bx = dxyz[b * 3 * N + n];
  const float by = dxyz[b * 3 * N + N + n];
  const float bz = dxyz[b * 3 * N + 2 * N + n];

  float d0 = 1e30f, d1 = 1e30f, d2 = 1e30f;
  int i0 = 0, i1 = 0, i2 = 0;

  #pragma unroll 4
  for (int s = 0; s < S; ++s) {
    float4 c = sp[s];  // wave-uniform address -> LDS broadcast
    float ex = bx - c.x, ey = by - c.y, ez = bz - c.z;
    float dist = fmaf(ex, ex, fmaf(ey, ey, ez * ez));
    if (dist < d2) {           // exec-masked slow path, rare after warm-up
      if (dist < d1) {
        d2 = d1; i2 = i1;
        if (dist < d0) { d1 = d0; i1 = i0; d0 = dist; i0 = s; }
        else           { d1 = dist; i1 = s; }
      } else {
        d2 = dist; i2 = s;
      }
    }
  }

  const float w0 = 1.f / (d0 + 1e-8f);
  const float w1 = 1.f / (d1 + 1e-8f);
  const float w2 = 1.f / (d2 + 1e-8f);
  const float inv = 1.f / (w0 + w1 + w2);
  const int base = (b * N + n) * 3;
  wgt[base + 0] = w0 * inv;
  wgt[base + 1] = w1 * inv;
  wgt[base + 2] = w2 * inv;
  idx[base + 0] = i0;
  idx[base + 1] = i1;
  idx[base + 2] = i2;
}

// ---------------------------------------------------------------------------
// K2: Z[b, s, o] = sum_c Ws[o, c] * sparse_data[b, c, s]   (o-contiguous!)
// Block = 64 sparse cols x 4 row-groups of 32 output channels.
// ---------------------------------------------------------------------------
__global__ __launch_bounds__(256) void zproj_kernel(
    const float* __restrict__ sdata, const float* __restrict__ cw,
    float* __restrict__ Z) {
  const int b = blockIdx.y;
  const int s = blockIdx.x * 64 + (threadIdx.x & 63);
  const int rg = __builtin_amdgcn_readfirstlane(threadIdx.x >> 6);
  const float* __restrict__ xp = sdata + b * CS * S + s;
  const float* __restrict__ wp = cw + rg * 32 * CIN + CD;  // Ws columns

  float acc[32];
  #pragma unroll
  for (int i = 0; i < 32; ++i) acc[i] = 0.f;

  #pragma unroll 4
  for (int c = 0; c < CS; ++c) {
    const float xv = xp[c * S];  // coalesced across the wave
    #pragma unroll
    for (int i = 0; i < 32; ++i)
      acc[i] = fmaf(wp[i * CIN + c], xv, acc[i]);  // wave-uniform -> s_load
  }

  float4* zp = reinterpret_cast<float4*>(Z + (b * S + s) * CO + rg * 32);
  #pragma unroll
  for (int i = 0; i < 8; ++i)
    zp[i] = make_float4(acc[4*i+0], acc[4*i+1], acc[4*i+2], acc[4*i+3]);
}

// ---------------------------------------------------------------------------
// K3: y[b, o, n] = sum_c Wd[o,c]*dense_data[b,c,n] + sum_k w_k * Z[b,idx_k,o]
// Writes raw (pre-BN) y straight into d_out's y region.
// ---------------------------------------------------------------------------
__global__ __launch_bounds__(256) void ygemm_kernel(
    const float* __restrict__ ddata, const float* __restrict__ cw,
    const float* __restrict__ Z, const float* __restrict__ wgt,
    const int* __restrict__ idx, float* __restrict__ y) {
  const int b = blockIdx.y;
  const int n = blockIdx.x * 64 + (threadIdx.x & 63);
  const int rg = __builtin_amdgcn_readfirstlane(threadIdx.x >> 6);
  const float* __restrict__ xp = ddata + b * CD * N + n;
  const float* __restrict__ wp = cw + rg * 32 * CIN;  // Wd columns

  float acc[32];
  #pragma unroll
  for (int i = 0; i < 32; ++i) acc[i] = 0.f;

  #pragma unroll 4
  for (int c = 0; c < CD; ++c) {
    const float xv = xp[c * N];  // coalesced across the wave
    #pragma unroll
    for (int i = 0; i < 32; ++i)
      acc[i] = fmaf(wp[i * CIN + c], xv, acc[i]);
  }

  const int pb = (b * N + n) * 3;
  #pragma unroll
  for (int k = 0; k < 3; ++k) {
    const float wk = wgt[pb + k];
    const int ik = idx[pb + k];
    const float4* zp =
        reinterpret_cast<const float4*>(Z + (b * S + ik) * CO + rg * 32);
    #pragma unroll
    for (int i = 0; i < 8; ++i) {
      float4 zv = zp[i];  // 128B contiguous per thread, L2-resident
      acc[4*i+0] = fmaf(wk, zv.x, acc[4*i+0]);
      acc[4*i+1] = fmaf(wk, zv.y, acc[4*i+1]);
      acc[4*i+2] = fmaf(wk, zv.z, acc[4*i+2]);
      acc[4*i+3] = fmaf(wk, zv.w, acc[4*i+3]);
    }
  }

  float* yp = y + b * CO * N + (rg * 32) * N + n;
  #pragma unroll
  for (int i = 0; i < 32; ++i) yp[i * N] = acc[i];  // coalesced per o-row
}

// ---------------------------------------------------------------------------
// K4: per-channel sum / sumsq over (B, N). Block per (o, b), atomics into ws.
// ---------------------------------------------------------------------------
__global__ __launch_bounds__(256) void stats_kernel(
    const float* __restrict__ y, float* __restrict__ stats) {
  const int o = blockIdx.x;
  const int b = blockIdx.y;
  const float4* yp = reinterpret_cast<const float4*>(y + (b * CO + o) * N);
  float s = 0.f, sq = 0.f;
  for (int j = threadIdx.x; j < N / 4; j += 256) {
    float4 v = yp[j];
    s  += v.x + v.y + v.z + v.w;
    sq += v.x * v.x + v.y * v.y + v.z * v.z + v.w * v.w;
  }
  __shared__ float ls[256];
  __shared__ float lq[256];
  ls[threadIdx.x] = s;
  lq[threadIdx.x] = sq;
  __syncthreads();
  for (int st = 128; st > 0; st >>= 1) {
    if (threadIdx.x < (unsigned)st) {
      ls[threadIdx.x] += ls[threadIdx.x + st];
      lq[threadIdx.x] += lq[threadIdx.x + st];
    }
    __syncthreads();
  }
  if (threadIdx.x == 0) {
    atomicAdd(&stats[o], ls[0]);
    atomicAdd(&stats[CO + o], lq[0]);
  }
}

// ---------------------------------------------------------------------------
// K4b: fold BN stats into per-channel scale/shift.
// ---------------------------------------------------------------------------
__global__ void scaleshift_kernel(const float* __restrict__ stats,
                                  const float* __restrict__ gamma,
                                  const float* __restrict__ beta,
                                  float* __restrict__ ss) {
  const int o = threadIdx.x;  // 128 threads
  const float invc = 1.f / (float)(B * N);
  const float m = stats[o] * invc;
  float v = stats[CO + o] * invc - m * m;
  v = fmaxf(v, 0.f);
  const float sc = gamma[o] / sqrtf(v + 1e-5f);
  ss[o] = sc;
  ss[CO + o] = beta[o] - m * sc;
}

// ---------------------------------------------------------------------------
// K5: in-place normalize + LeakyReLU(0.2) on d_out's y region (float4).
// ---------------------------------------------------------------------------
__global__ __launch_bounds__(256) void norm_kernel(float* __restrict__ y,
                                                   const float* __restrict__ ss) {
  const int i = blockIdx.x * 256 + threadIdx.x;  // float4 index
  const int o = (i >> 12) & (CO - 1);            // N/4 = 4096 float4 per (b,o)
  const float sc = ss[o];
  const float sh = ss[CO + o];
  float4* yp = reinterpret_cast<float4*>(y);
  float4 v = yp[i];
  float t;
  t = fmaf(v.x, sc, sh); v.x = fmaxf(t, 0.2f * t);
  t = fmaf(v.y, sc, sh); v.y = fmaxf(t, 0.2f * t);
  t = fmaf(v.z, sc, sh); v.z = fmaxf(t, 0.2f * t);
  t = fmaf(v.w, sc, sh); v.w = fmaxf(t, 0.2f * t);
  yp[i] = v;
}

// ---------------------------------------------------------------------------
extern "C" void kernel_launch(void* const* d_in, const int* in_sizes, int n_in,
                              void* d_out, int out_size, void* d_ws, size_t ws_size,
                              hipStream_t stream) {
  const float* dxyz  = (const float*)d_in[0];
  const float* sxyz  = (const float*)d_in[1];
  const float* ddata = (const float*)d_in[2];
  const float* sdata = (const float*)d_in[3];
  const float* cw    = (const float*)d_in[4];
  const float* gamma = (const float*)d_in[5];
  const float* beta  = (const float*)d_in[6];
  float* out = (float*)d_out;

  char* wsb = (char*)d_ws;
  float* wgt   = (float*)(wsb);                       // B*N*3 f32 = 786432 B
  int*   idx   = (int*)  (wsb + 786432);              // B*N*3 i32 = 786432 B
  float* Z     = (float*)(wsb + 1572864);             // B*S*CO f32 = 8388608 B
  float* stats = (float*)(wsb + 9961472);             // 256 f32
  float* ss    = (float*)(wsb + 9962496);             // 256 f32

  hipMemsetAsync(stats, 0, 2 * CO * sizeof(float), stream);

  knn_kernel  <<<dim3(N / 256, B), 256, 0, stream>>>(dxyz, sxyz, wgt, idx);
  zproj_kernel<<<dim3(S / 64,  B), 256, 0, stream>>>(sdata, cw, Z);
  ygemm_kernel<<<dim3(N / 64,  B), 256, 0, stream>>>(ddata, cw, Z, wgt, idx, out);
  stats_kernel<<<dim3(CO, B), 256, 0, stream>>>(out, stats);
  scaleshift_kernel<<<1, 128, 0, stream>>>(stats, gamma, beta, ss);
  norm_kernel <<<(B * CO * N / 4) / 256, 256, 0, stream>>>(out, ss);

  hipMemcpyAsync(out + (size_t)B * CO * N, dxyz, (size_t)B * 3 * N * sizeof(float),
                 hipMemcpyDeviceToDevice, stream);
}

// Round 2
// 416.940 us; speedup vs baseline: 1.3359x; 1.3359x over previous
//
#include <hip/hip_runtime.h>

// Problem constants (fixed shapes from setup_inputs)
constexpr int B  = 4;
constexpr int N  = 16384;   // dense points
constexpr int S  = 4096;    // sparse points
constexpr int CD = 128;     // dense feature channels
constexpr int CS = 256;     // sparse feature channels
constexpr int CO = 128;     // output channels
constexpr int CIN = CD + CS; // 384

// KNN decomposition
constexpr int NC = 8;      // S-chunks (independent blocks -> 2048 waves)
constexpr int CH = S / NC; // 512 sparse points per chunk
constexpr int P  = 4;      // dense points per thread (amortize LDS broadcast)

// ---------------------------------------------------------------------------
// K1a: per-chunk top-3. Branchless sorted-insert (cmp/cndmask/med3) so the
// compiler can software-pipeline the LDS reads; 4 points/thread so one
// ds_read_b128 feeds 72 VALU instructions.
// ---------------------------------------------------------------------------
__global__ __launch_bounds__(256) void knn_chunk_kernel(
    const float* __restrict__ dxyz, const float* __restrict__ sxyz,
    float* __restrict__ cdist, int* __restrict__ cidx) {
  __shared__ float4 sp[CH];
  const int b = blockIdx.z;
  const int c = blockIdx.y;
  const int nbase = blockIdx.x * (256 * P);
  const int t = threadIdx.x;

  const float* sb = sxyz + b * 3 * S + c * CH;
  for (int j = t; j < CH; j += 256)
    sp[j] = make_float4(sb[j], sb[S + j], sb[2 * S + j], 0.f);
  __syncthreads();

  float bx[P], by[P], bz[P];
  float d0[P], d1[P], d2[P];
  int   i0[P], i1[P], i2[P];
  #pragma unroll
  for (int p = 0; p < P; ++p) {
    const int n = nbase + p * 256 + t;
    bx[p] = dxyz[b * 3 * N + n];
    by[p] = dxyz[b * 3 * N + N + n];
    bz[p] = dxyz[b * 3 * N + 2 * N + n];
    d0[p] = d1[p] = d2[p] = 1e30f;
    i0[p] = i1[p] = i2[p] = 0;
  }

  #pragma unroll 4
  for (int j = 0; j < CH; ++j) {
    const float4 q = sp[j];            // wave-uniform LDS broadcast
    const int sg = c * CH + j;         // global sparse index
    #pragma unroll
    for (int p = 0; p < P; ++p) {
      const float ex = bx[p] - q.x, ey = by[p] - q.y, ez = bz[p] - q.z;
      const float x = fmaf(ex, ex, fmaf(ey, ey, ez * ez));
      const bool lt0 = x < d0[p];
      const bool lt1 = x < d1[p];
      const bool lt2 = x < d2[p];
      i2[p] = lt1 ? i1[p] : (lt2 ? sg : i2[p]);
      i1[p] = lt0 ? i0[p] : (lt1 ? sg : i1[p]);
      i0[p] = lt0 ? sg : i0[p];
      d2[p] = fminf(fmaxf(x, d1[p]), d2[p]);
      d1[p] = __builtin_amdgcn_fmed3f(x, d0[p], d1[p]);
      d0[p] = fminf(x, d0[p]);
    }
  }

  #pragma unroll
  for (int p = 0; p < P; ++p) {
    const int n = nbase + p * 256 + t;
    const size_t base = (((size_t)c * B + b) * N + n) * 3;
    cdist[base + 0] = d0[p]; cidx[base + 0] = i0[p];
    cdist[base + 1] = d1[p]; cidx[base + 1] = i1[p];
    cdist[base + 2] = d2[p]; cidx[base + 2] = i2[p];
  }
}

// ---------------------------------------------------------------------------
// K1b: merge per-chunk candidates (in chunk order = global index order, so
// strict < keeps the lowest-index winner on ties, matching the sequential
// scan) and emit normalized inverse-distance weights.
// ---------------------------------------------------------------------------
__global__ __launch_bounds__(256) void knn_merge_kernel(
    const float* __restrict__ cdist, const int* __restrict__ cidx,
    float* __restrict__ wgt, int* __restrict__ idx) {
  const int gid = blockIdx.x * 256 + threadIdx.x;  // = b*N + n
  float d0 = 1e30f, d1 = 1e30f, d2 = 1e30f;
  int i0 = 0, i1 = 0, i2 = 0;
  #pragma unroll
  for (int c = 0; c < NC; ++c) {
    const size_t base = ((size_t)c * B * N + gid) * 3;
    #pragma unroll
    for (int k = 0; k < 3; ++k) {
      const float x = cdist[base + k];
      const int sg = cidx[base + k];
      const bool lt0 = x < d0;
      const bool lt1 = x < d1;
      const bool lt2 = x < d2;
      i2 = lt1 ? i1 : (lt2 ? sg : i2);
      i1 = lt0 ? i0 : (lt1 ? sg : i1);
      i0 = lt0 ? sg : i0;
      d2 = fminf(fmaxf(x, d1), d2);
      d1 = __builtin_amdgcn_fmed3f(x, d0, d1);
      d0 = fminf(x, d0);
    }
  }
  const float w0 = 1.f / (d0 + 1e-8f);
  const float w1 = 1.f / (d1 + 1e-8f);
  const float w2 = 1.f / (d2 + 1e-8f);
  const float inv = 1.f / (w0 + w1 + w2);
  const size_t base = (size_t)gid * 3;
  wgt[base + 0] = w0 * inv;
  wgt[base + 1] = w1 * inv;
  wgt[base + 2] = w2 * inv;
  idx[base + 0] = i0;
  idx[base + 1] = i1;
  idx[base + 2] = i2;
}

// ---------------------------------------------------------------------------
// K2: Z[b, s, o] = sum_c Ws[o, c] * sparse_data[b, c, s]   (o-contiguous!)
// ---------------------------------------------------------------------------
__global__ __launch_bounds__(256) void zproj_kernel(
    const float* __restrict__ sdata, const float* __restrict__ cw,
    float* __restrict__ Z) {
  const int b = blockIdx.y;
  const int s = blockIdx.x * 64 + (threadIdx.x & 63);
  const int rg = __builtin_amdgcn_readfirstlane(threadIdx.x >> 6);
  const float* __restrict__ xp = sdata + b * CS * S + s;
  const float* __restrict__ wp = cw + rg * 32 * CIN + CD;  // Ws columns

  float acc[32];
  #pragma unroll
  for (int i = 0; i < 32; ++i) acc[i] = 0.f;

  #pragma unroll 4
  for (int c = 0; c < CS; ++c) {
    const float xv = xp[c * S];  // coalesced across the wave
    #pragma unroll
    for (int i = 0; i < 32; ++i)
      acc[i] = fmaf(wp[i * CIN + c], xv, acc[i]);  // wave-uniform -> s_load
  }

  float4* zp = reinterpret_cast<float4*>(Z + (b * S + s) * CO + rg * 32);
  #pragma unroll
  for (int i = 0; i < 8; ++i)
    zp[i] = make_float4(acc[4*i+0], acc[4*i+1], acc[4*i+2], acc[4*i+3]);
}

// ---------------------------------------------------------------------------
// K3: y[b, o, n] = sum_c Wd[o,c]*dense_data[b,c,n] + sum_k w_k * Z[b,idx_k,o]
// ---------------------------------------------------------------------------
__global__ __launch_bounds__(256) void ygemm_kernel(
    const float* __restrict__ ddata, const float* __restrict__ cw,
    const float* __restrict__ Z, const float* __restrict__ wgt,
    const int* __restrict__ idx, float* __restrict__ y) {
  const int b = blockIdx.y;
  const int n = blockIdx.x * 64 + (threadIdx.x & 63);
  const int rg = __builtin_amdgcn_readfirstlane(threadIdx.x >> 6);
  const float* __restrict__ xp = ddata + b * CD * N + n;
  const float* __restrict__ wp = cw + rg * 32 * CIN;  // Wd columns

  float acc[32];
  #pragma unroll
  for (int i = 0; i < 32; ++i) acc[i] = 0.f;

  #pragma unroll 4
  for (int c = 0; c < CD; ++c) {
    const float xv = xp[c * N];
    #pragma unroll
    for (int i = 0; i < 32; ++i)
      acc[i] = fmaf(wp[i * CIN + c], xv, acc[i]);
  }

  const int pb = (b * N + n) * 3;
  #pragma unroll
  for (int k = 0; k < 3; ++k) {
    const float wk = wgt[pb + k];
    const int ik = idx[pb + k];
    const float4* zp =
        reinterpret_cast<const float4*>(Z + (b * S + ik) * CO + rg * 32);
    #pragma unroll
    for (int i = 0; i < 8; ++i) {
      float4 zv = zp[i];
      acc[4*i+0] = fmaf(wk, zv.x, acc[4*i+0]);
      acc[4*i+1] = fmaf(wk, zv.y, acc[4*i+1]);
      acc[4*i+2] = fmaf(wk, zv.z, acc[4*i+2]);
      acc[4*i+3] = fmaf(wk, zv.w, acc[4*i+3]);
    }
  }

  float* yp = y + b * CO * N + (rg * 32) * N + n;
  #pragma unroll
  for (int i = 0; i < 32; ++i) yp[i * N] = acc[i];
}

// ---------------------------------------------------------------------------
// K4: per-channel sum / sumsq over (B, N).
// ---------------------------------------------------------------------------
__global__ __launch_bounds__(256) void stats_kernel(
    const float* __restrict__ y, float* __restrict__ stats) {
  const int o = blockIdx.x;
  const int b = blockIdx.y;
  const float4* yp = reinterpret_cast<const float4*>(y + (b * CO + o) * N);
  float s = 0.f, sq = 0.f;
  for (int j = threadIdx.x; j < N / 4; j += 256) {
    float4 v = yp[j];
    s  += v.x + v.y + v.z + v.w;
    sq += v.x * v.x + v.y * v.y + v.z * v.z + v.w * v.w;
  }
  __shared__ float ls[256];
  __shared__ float lq[256];
  ls[threadIdx.x] = s;
  lq[threadIdx.x] = sq;
  __syncthreads();
  for (int st = 128; st > 0; st >>= 1) {
    if (threadIdx.x < (unsigned)st) {
      ls[threadIdx.x] += ls[threadIdx.x + st];
      lq[threadIdx.x] += lq[threadIdx.x + st];
    }
    __syncthreads();
  }
  if (threadIdx.x == 0) {
    atomicAdd(&stats[o], ls[0]);
    atomicAdd(&stats[CO + o], lq[0]);
  }
}

// ---------------------------------------------------------------------------
// K4b: fold BN stats into per-channel scale/shift.
// ---------------------------------------------------------------------------
__global__ void scaleshift_kernel(const float* __restrict__ stats,
                                  const float* __restrict__ gamma,
                                  const float* __restrict__ beta,
                                  float* __restrict__ ss) {
  const int o = threadIdx.x;  // 128 threads
  const float invc = 1.f / (float)(B * N);
  const float m = stats[o] * invc;
  float v = stats[CO + o] * invc - m * m;
  v = fmaxf(v, 0.f);
  const float sc = gamma[o] / sqrtf(v + 1e-5f);
  ss[o] = sc;
  ss[CO + o] = beta[o] - m * sc;
}

// ---------------------------------------------------------------------------
// K5: in-place normalize + LeakyReLU(0.2) on d_out's y region (float4).
// ---------------------------------------------------------------------------
__global__ __launch_bounds__(256) void norm_kernel(float* __restrict__ y,
                                                   const float* __restrict__ ss) {
  const int i = blockIdx.x * 256 + threadIdx.x;  // float4 index
  const int o = (i >> 12) & (CO - 1);            // N/4 = 4096 float4 per (b,o)
  const float sc = ss[o];
  const float sh = ss[CO + o];
  float4* yp = reinterpret_cast<float4*>(y);
  float4 v = yp[i];
  float t;
  t = fmaf(v.x, sc, sh); v.x = fmaxf(t, 0.2f * t);
  t = fmaf(v.y, sc, sh); v.y = fmaxf(t, 0.2f * t);
  t = fmaf(v.z, sc, sh); v.z = fmaxf(t, 0.2f * t);
  t = fmaf(v.w, sc, sh); v.w = fmaxf(t, 0.2f * t);
  yp[i] = v;
}

// ---------------------------------------------------------------------------
extern "C" void kernel_launch(void* const* d_in, const int* in_sizes, int n_in,
                              void* d_out, int out_size, void* d_ws, size_t ws_size,
                              hipStream_t stream) {
  const float* dxyz  = (const float*)d_in[0];
  const float* sxyz  = (const float*)d_in[1];
  const float* ddata = (const float*)d_in[2];
  const float* sdata = (const float*)d_in[3];
  const float* cw    = (const float*)d_in[4];
  const float* gamma = (const float*)d_in[5];
  const float* beta  = (const float*)d_in[6];
  float* out = (float*)d_out;

  char* wsb = (char*)d_ws;
  // Persistent region
  float* wgt   = (float*)(wsb);                 // B*N*3 f32 = 786432 B
  int*   idx   = (int*)  (wsb + 786432);        // B*N*3 i32 = 786432 B
  // Phase 1 (KNN): candidate buffers. Phase 2 (GEMM): Z aliases this region
  // (knn_merge completes before zproj writes — same stream).
  float* cdist = (float*)(wsb + 1572864);       // NC*B*N*3 f32 = 6291456 B
  int*   cidx  = (int*)  (wsb + 7864320);       // NC*B*N*3 i32 = 6291456 B
  float* Z     = (float*)(wsb + 1572864);       // B*S*CO f32 = 8388608 B
  float* stats = (float*)(wsb + 14155776);      // 256 f32
  float* ss    = (float*)(wsb + 14156800);      // 256 f32

  hipMemsetAsync(stats, 0, 2 * CO * sizeof(float), stream);

  knn_chunk_kernel<<<dim3(N / (256 * P), NC, B), 256, 0, stream>>>(dxyz, sxyz, cdist, cidx);
  knn_merge_kernel<<<dim3(B * N / 256), 256, 0, stream>>>(cdist, cidx, wgt, idx);
  zproj_kernel<<<dim3(S / 64,  B), 256, 0, stream>>>(sdata, cw, Z);
  ygemm_kernel<<<dim3(N / 64,  B), 256, 0, stream>>>(ddata, cw, Z, wgt, idx, out);
  stats_kernel<<<dim3(CO, B), 256, 0, stream>>>(out, stats);
  scaleshift_kernel<<<1, 128, 0, stream>>>(stats, gamma, beta, ss);
  norm_kernel <<<(B * CO * N / 4) / 256, 256, 0, stream>>>(out, ss);

  hipMemcpyAsync(out + (size_t)B * CO * N, dxyz, (size_t)B * 3 * N * sizeof(float),
                 hipMemcpyDeviceToDevice, stream);
}